// Round 12
// baseline (315.952 us; speedup 1.0000x reference)
//
#include <hip/hip_runtime.h>

#define NEG_SLOPE 0.01f

constexpr int N_NODES_C = 50000;
constexpr int N_EDGES_C = 800000;
constexpr int M_PAD = 50048;      // 391 * 128
constexpr int META_CAP = 950016;  // padded CSR capacity: 800000 + <=150000 pad + slack

typedef short bf16x8 __attribute__((ext_vector_type(8)));
typedef float f32x4 __attribute__((ext_vector_type(4)));

__device__ inline unsigned short f2bf(float f) {
  unsigned int u = __float_as_uint(f);
  u += 0x7FFF + ((u >> 16) & 1);  // round-to-nearest-even
  return (unsigned short)(u >> 16);
}
__device__ inline float bf2f(unsigned int h16) {
  return __uint_as_float(h16 << 16);
}

// ---------------- fused preprocessing (coalescing-fixed, R9) ----------------
// lane-contiguous linear mapping: lane l reads float4 at +l*16B (1KB/wave-
// inst), writes bf16 uint2 at +l*8B. hist every 4th block overlaps atomics.
constexpr int NB_CONV4 = (N_NODES_C * 64) / 1024;       // 3125
constexpr int NB_Z = 1;                                 // xb padding zero-fill
constexpr int NB_W1 = (256 * 256) / 256;                // 256
constexpr int NB_W2 = (256 * 128) / 256;                // 128
constexpr int NB_HIST = ((N_EDGES_C / 4) + 255) / 256;  // 782
constexpr int NB_NONH = NB_CONV4 + NB_Z + NB_W1 + NB_W2;  // 3510
constexpr int NB_PRE = NB_NONH + NB_HIST;               // 4292
constexpr int HIST_REGION = NB_HIST * 4;                // 3128

__global__ __launch_bounds__(256) void pre_kernel(
    const float* __restrict__ x, const float* __restrict__ w1,
    const float* __restrict__ w2, const int* __restrict__ dst,
    unsigned short* __restrict__ xb, unsigned short* __restrict__ w1T,
    unsigned short* __restrict__ w2T, int* __restrict__ counts) {
  const int bx = blockIdx.x;
  const int tid = threadIdx.x;
  int l, isHist = 0, h = 0;
  if (bx < HIST_REGION) {
    if ((bx & 3) == 3) { isHist = 1; h = bx >> 2; l = 0; }
    else l = bx - ((bx + 1) >> 2);
  } else {
    l = bx - NB_HIST;
  }

  if (isHist) {
    int e = (h * 256 + tid) * 4;
    if (e < N_EDGES_C) {
      int4 d4 = *(const int4*)(dst + e);
      atomicAdd(&counts[d4.x], 1);
      atomicAdd(&counts[d4.y], 1);
      atomicAdd(&counts[d4.z], 1);
      atomicAdd(&counts[d4.w], 1);
    }
  } else if (l < NB_CONV4) {
    const float4* xv = (const float4*)x;
#pragma unroll
    for (int i = 0; i < 4; ++i) {
      int g = l * 1024 + i * 256 + tid;  // global float4 index, lane-contiguous
      float4 f = xv[g];
      uint2 o;
      o.x = f2bf(f.x) | ((unsigned)f2bf(f.y) << 16);
      o.y = f2bf(f.z) | ((unsigned)f2bf(f.w) << 16);
      *(uint2*)(xb + (size_t)g * 4) = o;
    }
  } else if (l == NB_CONV4) {
    unsigned short* base = xb + (size_t)N_NODES_C * 256;
    uint4 z = make_uint4(0, 0, 0, 0);
#pragma unroll
    for (int i = 0; i < 6; ++i)
      *(uint4*)(base + (size_t)(i * 256 + tid) * 8) = z;
  } else if (l < NB_CONV4 + NB_Z + NB_W1) {
    int idx = (l - NB_CONV4 - NB_Z) * 256 + tid;  // over [N=256][K=256]
    int n = idx >> 8, k = idx & 255;
    w1T[idx] = f2bf(w1[(size_t)k * 256 + n]);
  } else {
    int idx = (l - NB_CONV4 - NB_Z - NB_W1) * 256 + tid;  // over [N=128][K=256]
    int n = idx >> 8, k = idx & 255;
    w2T[idx] = f2bf(w2[(size_t)k * 128 + n]);
  }
}

// ---------------- degree histogram (64 bins + per-block counts) ----------
// R11 post-timing divergence root cause: gclaim atomics made node->rank
// NONDETERMINISTIC per replay, so any staleness maps to a different node's
// edges (O(1) errors). Fix: fully deterministic (bin, block, wave, lane)
// rank order. hist emits per-block bin counts for block-offset computation.
constexpr int NB_NODE = (N_NODES_C + 255) / 256;  // 196
constexpr int NB_SCAT = (M_PAD + 255) / 256;      // 196

__global__ __launch_bounds__(256) void hist_kernel(const int* __restrict__ counts,
                                                   int* __restrict__ hist2,
                                                   int* __restrict__ ehist,
                                                   int* __restrict__ blk_cnt,
                                                   int* __restrict__ blk_e63) {
  __shared__ int lh[64], le[64];
  const int t = threadIdx.x;
  if (t < 64) { lh[t] = 0; le[t] = 0; }
  __syncthreads();
  const int i = blockIdx.x * 256 + t;
  if (i < N_NODES_C) {
    int d = counts[i];
    int bin = d < 63 ? d : 63;
    atomicAdd(&lh[bin], 1);
    atomicAdd(&le[bin], (d + 3) & ~3);  // 4-aligned (padded) segment length
  }
  __syncthreads();
  if (t < 64) {
    if (lh[t]) atomicAdd(&hist2[t], lh[t]);
    if (le[t]) atomicAdd(&ehist[t], le[t]);
    blk_cnt[blockIdx.x * 64 + t] = lh[t];
    if (t == 63) blk_e63[blockIdx.x] = le[63];
  }
}

// ---------------- deterministic degree-sorted permuted-CSR scatter --------
// rank = nbase[bin] + (earlier blocks' bin count) + (earlier waves' bin
// count) + (ballot rank within wave). For bin<63 padded length is constant
// (d4 = (bin+3)&~3) so edge offsets are rank*d4; bin63 (never occurs at
// Poisson(16), kept correct) uses a shfl prefix scan. Zero atomics ->
// bit-identical perm/nstart/ndeg/cursor/s_meta-pads every replay.
__global__ __launch_bounds__(256) void scatter_kernel(
    const int* __restrict__ counts, const int* __restrict__ hist2,
    const int* __restrict__ ehist, const int* __restrict__ blk_cnt,
    const int* __restrict__ blk_e63, int* __restrict__ perm,
    int* __restrict__ nstart, int* __restrict__ ndeg,
    int* __restrict__ cursor, unsigned* __restrict__ s_meta) {
  __shared__ int nbase[64], ebase[64], boffn[64], wcnt[4][64], we63s[4];
  __shared__ int boffe63;
  const int t = threadIdx.x;
  const int wv = t >> 6, lane = t & 63;

  if (t < 64) {
    // global exclusive bucket bases (deterministic: hist sums)
    int hv = hist2[t], ev = ehist[t];
    int xs = hv, xe = ev;
#pragma unroll
    for (int off = 1; off < 64; off <<= 1) {
      int a = __shfl_up(xs, off);
      int b = __shfl_up(xe, off);
      if (lane >= off) { xs += a; xe += b; }
    }
    nbase[t] = xs - hv;
    ebase[t] = xe - ev;
    // block offset for this bin: sum of earlier blocks' counts
    int bn = 0;
    for (int b = 0; b < (int)blockIdx.x; ++b) bn += blk_cnt[b * 64 + t];
    boffn[t] = bn;
  }
  if (t == 64) {  // wave 1, lane 0: bin-63 padded-edge block offset
    int be = 0;
    for (int b = 0; b < (int)blockIdx.x; ++b) be += blk_e63[b];
    boffe63 = be;
  }

  const int idx = blockIdx.x * 256 + t;
  int d = -1, bin = 0, d4 = 0;
  if (idx < N_NODES_C) {
    d = counts[idx];
    bin = d < 63 ? d : 63;
    d4 = (d + 3) & ~3;
  } else if (idx < M_PAD) {
    perm[idx] = idx;  // padding ranks map to themselves, zero-length segment
    nstart[idx] = 0;
    ndeg[idx] = 0;
  }

  // intra-wave stable rank via ballot loop (lane order = deterministic)
  int rank_w = 0, mycnt = 0;
  for (int B = 0; B < 64; ++B) {
    unsigned long long m = __ballot(d >= 0 && bin == B);
    if (d >= 0 && bin == B)
      rank_w = __popcll(m & ((1ull << lane) - 1));
    if (lane == B) mycnt = __popcll(m);
  }
  // bin-63 weighted exclusive prefix (d4 varies within bin 63)
  int c63 = (d >= 0 && bin == 63) ? d4 : 0;
  int sc = c63;
#pragma unroll
  for (int off = 1; off < 64; off <<= 1) {
    int u = __shfl_up(sc, off);
    if (lane >= off) sc += u;
  }
  const int excl63 = sc - c63;
  const int tot63 = __shfl(sc, 63);
  wcnt[wv][lane] = mycnt;  // lane l holds this wave's count for bin l
  if (lane == 0) we63s[wv] = tot63;
  __syncthreads();

  if (d >= 0) {
    int rank_blk = rank_w;
    int e63off = excl63;
    for (int w = 0; w < wv; ++w) {
      rank_blk += wcnt[w][bin];
      e63off += we63s[w];
    }
    const int grank = nbase[bin] + boffn[bin] + rank_blk;
    const int d4b = (bin + 3) & ~3;  // == d4 for bin<63
    const int estart = (bin < 63)
        ? ebase[bin] + (boffn[bin] + rank_blk) * d4b
        : ebase[63] + boffe63 + e63off;
    perm[grank] = idx;
    nstart[grank] = estart;
    ndeg[grank] = d;
    cursor[idx] = estart;
    for (int j = d; j < d4; ++j) s_meta[estart + j] = 0;  // zero-weight pads
  }
}

// ---------------- shared GEMM tile (device fn) ----------------
// C natural [M_PAD][ldc] row-major (agg reads full contiguous rows)

#define GLOAD_LDS16(g, l)                                              \
  __builtin_amdgcn_global_load_lds(                                    \
      (__attribute__((address_space(1))) void*)(g),                    \
      (__attribute__((address_space(3))) void*)(l), 16, 0, 0)

__device__ __forceinline__ void gemm_tile(
    const unsigned short* __restrict__ A,   // [M_PAD][256] bf16
    const unsigned short* __restrict__ BT,  // [N][256] bf16
    unsigned short* __restrict__ C,         // [M_PAD][ldc] natural
    int N, int ldc, int row0, int col0, short* Asm, short* Bsm) {
  constexpr int K = 256;
  const int tid = threadIdx.x;
  const int lane = tid & 63, wave = tid >> 6;
  const int wm = wave & 1, wn = wave >> 1;

  const int ch0 = wave * 2, ch1 = wave * 2 + 1;
  const int o0 = ch0 * 512 + lane * 8;
  const int o1 = ch1 * 512 + lane * 8;
  const int r0 = o0 >> 5, c0 = o0 & 31;
  const int r1 = o1 >> 5, c1 = o1 & 31;

  f32x4 acc[4][4] = {};

  for (int k0 = 0; k0 < K; k0 += 32) {
    GLOAD_LDS16(A + (size_t)(row0 + r0) * K + k0 + c0, &Asm[ch0 * 512]);
    GLOAD_LDS16(A + (size_t)(row0 + r1) * K + k0 + c1, &Asm[ch1 * 512]);
    GLOAD_LDS16(BT + (size_t)(col0 + r0) * K + k0 + c0, &Bsm[ch0 * 512]);
    GLOAD_LDS16(BT + (size_t)(col0 + r1) * K + k0 + c1, &Bsm[ch1 * 512]);
    __builtin_amdgcn_s_waitcnt(0);
    __syncthreads();

    bf16x8 af[4], bf[4];
#pragma unroll
    for (int mt = 0; mt < 4; ++mt)
      af[mt] = *(const bf16x8*)&Asm[(wm * 64 + mt * 16 + (lane & 15)) * 32 + (lane >> 4) * 8];
#pragma unroll
    for (int nt = 0; nt < 4; ++nt)
      bf[nt] = *(const bf16x8*)&Bsm[(wn * 64 + nt * 16 + (lane & 15)) * 32 + (lane >> 4) * 8];
#pragma unroll
    for (int mt = 0; mt < 4; ++mt)
#pragma unroll
      for (int nt = 0; nt < 4; ++nt)
        acc[mt][nt] = __builtin_amdgcn_mfma_f32_16x16x32_bf16(af[mt], bf[nt], acc[mt][nt], 0, 0, 0);
    __syncthreads();
  }

  const int cl = lane & 15, rq = (lane >> 4) * 4;
#pragma unroll
  for (int mt = 0; mt < 4; ++mt) {
    const int rbase = row0 + wm * 64 + mt * 16 + rq;
#pragma unroll
    for (int nt = 0; nt < 4; ++nt) {
      const int col = col0 + wn * 64 + nt * 16 + cl;
#pragma unroll
      for (int i = 0; i < 4; ++i)
        C[(size_t)(rbase + i) * ldc + col] = f2bf(acc[mt][nt][i]);
    }
  }
}

// ---------------- fused fill + gemm1 ----------------
// Plain stores for s_meta (NT stores removed: cross-XCD stale-L2 hazard on
// graph replay -- R11 root-cause suspect #2).
constexpr int NB_GEMM1 = 2 * (M_PAD / 128);              // 782
constexpr int NB_FILL = ((N_EDGES_C / 4) + 255) / 256;   // 782 (== NB_GEMM1)

__global__ __launch_bounds__(256) void fill_gemm1_kernel(
    const unsigned short* __restrict__ A, const unsigned short* __restrict__ BT,
    unsigned short* __restrict__ C, const int* __restrict__ src,
    const int* __restrict__ dst, const float* __restrict__ ew,
    int* __restrict__ cursor, unsigned* __restrict__ s_meta) {
  __shared__ short Asm[128 * 32];
  __shared__ short Bsm[128 * 32];
  const int b = blockIdx.x;
  if ((b & 1) == 0) {
    const int t = b >> 1;  // [0, NB_GEMM1)
    gemm_tile(A, BT, C, 256, 256, (t >> 1) * 128, (t & 1) * 128, Asm, Bsm);
  } else {
    const int g = (b >> 1) * 256 + threadIdx.x;  // 4-edge group id
    const int e = g * 4;
    if (e < N_EDGES_C) {
      int4 d4 = *(const int4*)(dst + e);
      int4 s4 = *(const int4*)(src + e);
      float4 w4 = *(const float4*)(ew + e);
      unsigned m0 = (unsigned)s4.x | ((unsigned)f2bf(w4.x) << 16);
      unsigned m1 = (unsigned)s4.y | ((unsigned)f2bf(w4.y) << 16);
      unsigned m2 = (unsigned)s4.z | ((unsigned)f2bf(w4.z) << 16);
      unsigned m3 = (unsigned)s4.w | ((unsigned)f2bf(w4.w) << 16);
      int p0 = atomicAdd(&cursor[d4.x], 1);
      int p1 = atomicAdd(&cursor[d4.y], 1);
      int p2 = atomicAdd(&cursor[d4.z], 1);
      int p3 = atomicAdd(&cursor[d4.w], 1);
      s_meta[p0] = m0;
      s_meta[p1] = m1;
      s_meta[p2] = m2;
      s_meta[p3] = m3;
    }
  }
}

__global__ __launch_bounds__(256) void gemm2_kernel(
    const unsigned short* __restrict__ A, const unsigned short* __restrict__ BT,
    unsigned short* __restrict__ C) {
  __shared__ short Asm[128 * 32];
  __shared__ short Bsm[128 * 32];
  gemm_tile(A, BT, C, 128, 128, blockIdx.x * 128, 0, Asm, Bsm);
}

// ---------------- single-pass full-row aggregation (R8 structure) ---------
// one wave = one node, lane l owns dims [l*DPL, l*DPL+DPL); each edge = ONE
// coalesced contiguous row load (512B/256B per wave-inst); 2-quad meta
// software-prefetch pipeline (8 edges ahead) -- the structure R8 measured
// best (R9's split-lane no-prefetch variant regressed 60->72us).

__device__ __forceinline__ void rfma_256(float* acc, unsigned m,
                                         const unsigned short* __restrict__ tp) {
  uint2 v = *(const uint2*)(tp + (size_t)(m & 0xffffu) * 256);
  float wt = bf2f(m >> 16);
  acc[0] += bf2f(v.x & 0xffffu) * wt;
  acc[1] += bf2f(v.x >> 16) * wt;
  acc[2] += bf2f(v.y & 0xffffu) * wt;
  acc[3] += bf2f(v.y >> 16) * wt;
}

__device__ __forceinline__ void rfma_128(float* acc, unsigned m,
                                         const unsigned short* __restrict__ tp) {
  unsigned v = *(const unsigned*)(tp + (size_t)(m & 0xffffu) * 128);
  float wt = bf2f(m >> 16);
  acc[0] += bf2f(v & 0xffffu) * wt;
  acc[1] += bf2f(v >> 16) * wt;
}

template <int OUT_D, bool OUT_BF16>
__global__ __launch_bounds__(256) void agg_row_kernel(
    const unsigned short* __restrict__ sup,   // [M_PAD][OUT_D] natural bf16
    const unsigned* __restrict__ s_meta,      // permuted CSR, 4-aligned segs
    const int* __restrict__ nstart, const int* __restrict__ ndeg,
    const int* __restrict__ perm, const float* __restrict__ bias,
    unsigned short* __restrict__ out_bf, float* __restrict__ out_f, int n_total) {
  constexpr int DPL = OUT_D / 64;  // dims per lane: 4 (layer1) / 2 (layer2)
  const int tid = threadIdx.x;
  const int wv = tid >> 6;   // wave in block (0..3) = node
  const int lane = tid & 63;
  const int idx = blockIdx.x * 4 + wv;
  if (idx >= n_total) return;
  const int n = perm[idx];
  const bool valid = n < N_NODES_C;
  const unsigned short* tp = sup + lane * DPL;

  float acc[DPL] = {};
  const int s = nstart[idx];
  const int nq = (ndeg[idx] + 3) >> 2;  // 4-edge quads (pads are zero-weight)
  const uint4* mp = (const uint4*)(s_meta + s);

#define RFMA(mm)                              \
  do {                                        \
    if (OUT_D == 256) rfma_256(acc, mm, tp);  \
    else rfma_128(acc, mm, tp);               \
  } while (0)

  if (nq > 0) {
    uint4 m0 = mp[0];
    uint4 m1 = (nq > 1) ? mp[1] : make_uint4(0, 0, 0, 0);
    int q = 0;
    for (; q + 2 < nq; q += 2) {
      uint4 p0 = mp[q + 2];
      uint4 p1 = mp[q + 3];  // may read 16B past segment end (buffer slack)
      RFMA(m0.x); RFMA(m0.y); RFMA(m0.z); RFMA(m0.w);
      RFMA(m1.x); RFMA(m1.y); RFMA(m1.z); RFMA(m1.w);
      m0 = p0;
      m1 = p1;
    }
    RFMA(m0.x); RFMA(m0.y); RFMA(m0.z); RFMA(m0.w);
    if (q + 1 < nq) { RFMA(m1.x); RFMA(m1.y); RFMA(m1.z); RFMA(m1.w); }
  }
#undef RFMA

  const int dbase = lane * DPL;
  if (OUT_BF16) {
    unsigned short o[DPL];
#pragma unroll
    for (int j = 0; j < DPL; ++j) {
      if (valid) {
        float v = acc[j] + bias[dbase + j];
        v = v >= 0.f ? v : NEG_SLOPE * v;
        o[j] = f2bf(v);
      } else {
        o[j] = 0;
      }
    }
    uint2 pk;
    pk.x = o[0] | ((unsigned)o[1] << 16);
    pk.y = o[2] | ((unsigned)o[3] << 16);
    *(uint2*)(out_bf + (size_t)n * OUT_D + dbase) = pk;  // 8B/lane coalesced
  } else if (valid) {
    float r[DPL];
#pragma unroll
    for (int j = 0; j < DPL; ++j) {
      float v = acc[j] + bias[dbase + j];
      r[j] = v >= 0.f ? v : NEG_SLOPE * v;
    }
    *(float2*)(out_f + (size_t)n * OUT_D + dbase) = make_float2(r[0], r[1]);
  }
}

// ---------------- launch ----------------

extern "C" void kernel_launch(void* const* d_in, const int* in_sizes, int n_in,
                              void* d_out, int out_size, void* d_ws, size_t ws_size,
                              hipStream_t stream) {
  const float* x  = (const float*)d_in[0];   // [50000,256]
  const float* w1 = (const float*)d_in[1];   // [256,256]
  const float* b1 = (const float*)d_in[2];   // [256]
  const float* w2 = (const float*)d_in[3];   // [256,128]
  const float* b2 = (const float*)d_in[4];   // [128]
  const int*   src = (const int*)d_in[5];    // [800000]
  const int*   dst = (const int*)d_in[6];    // [800000]
  const float* ew  = (const float*)d_in[7];  // [800000]
  float* out = (float*)d_out;                // [50000,128]

  unsigned short* xb   = (unsigned short*)d_ws;              // M_PAD*256
  unsigned short* a2b  = xb + (size_t)M_PAD * 256;           // M_PAD*256
  unsigned short* sup1 = a2b + (size_t)M_PAD * 256;          // [M_PAD][256]
  unsigned short* sup2 = sup1 + (size_t)M_PAD * 256;         // [M_PAD][128]
  unsigned short* w1T  = sup2 + (size_t)M_PAD * 128;         // 256*256
  unsigned short* w2T  = w1T + 256 * 256;                    // 128*256
  int* counts  = (int*)(w2T + 128 * 256);                    // 50000
  int* cursor  = counts + N_NODES_C;                         // 50000
  int* perm    = cursor + N_NODES_C;                         // M_PAD
  int* nstart  = perm + M_PAD;                               // M_PAD
  int* ndeg    = nstart + M_PAD;                             // M_PAD
  int* hist2   = ndeg + M_PAD;                               // 64
  int* ehist   = hist2 + 64;                                 // 64
  int* zspare  = ehist + 64;                                 // 128 (memset pad)
  int* blk_cnt = zspare + 128;                               // 196*64 = 12544
  int* blk_e63 = blk_cnt + NB_NODE * 64;                     // 196
  unsigned* s_meta = (unsigned*)(blk_e63 + NB_NODE);         // META_CAP * 4B

  // zero counts + {hist2, ehist, spare} (contiguous 256 ints)
  hipMemsetAsync(counts, 0, N_NODES_C * sizeof(int), stream);
  hipMemsetAsync(hist2, 0, 256 * sizeof(int), stream);
  pre_kernel<<<NB_PRE, 256, 0, stream>>>(x, w1, w2, dst, xb, w1T, w2T, counts);

  // degree histogram (+ per-block counts) -> deterministic permuted-CSR scatter
  hist_kernel<<<NB_NODE, 256, 0, stream>>>(counts, hist2, ehist, blk_cnt, blk_e63);
  scatter_kernel<<<NB_SCAT, 256, 0, stream>>>(counts, hist2, ehist, blk_cnt,
                                              blk_e63, perm, nstart, ndeg,
                                              cursor, s_meta);

  // fused: CSR bucket fill (into permuted layout) + gemm1 (one dispatch)
  fill_gemm1_kernel<<<NB_GEMM1 + NB_FILL, 256, 0, stream>>>(
      xb, w1T, sup1, src, dst, ew, cursor, s_meta);

  // layer-1 aggregation -> a2b (bf16, lrelu+bias fused); 4 nodes/block
  agg_row_kernel<256, true><<<M_PAD / 4, 256, 0, stream>>>(
      sup1, s_meta, nstart, ndeg, perm, b1, a2b, nullptr, M_PAD);

  // layer 2
  gemm2_kernel<<<M_PAD / 128, 256, 0, stream>>>(a2b, w2T, sup2);
  agg_row_kernel<128, false><<<N_NODES_C / 4, 256, 0, stream>>>(
      sup2, s_meta, nstart, ndeg, perm, b2, nullptr, out, N_NODES_C);
}

// Round 13
// 284.137 us; speedup vs baseline: 1.1120x; 1.1120x over previous
//
#include <hip/hip_runtime.h>

#define NEG_SLOPE 0.01f

constexpr int N_NODES_C = 50000;
constexpr int N_EDGES_C = 800000;
constexpr int M_PAD = 50048;      // 391 * 128
constexpr int META_CAP = 950016;  // padded CSR capacity: 800000 + <=150000 pad + slack

typedef short bf16x8 __attribute__((ext_vector_type(8)));
typedef float f32x4 __attribute__((ext_vector_type(4)));

__device__ inline unsigned short f2bf(float f) {
  unsigned int u = __float_as_uint(f);
  u += 0x7FFF + ((u >> 16) & 1);  // round-to-nearest-even
  return (unsigned short)(u >> 16);
}
__device__ inline float bf2f(unsigned int h16) {
  return __uint_as_float(h16 << 16);
}

// ---------------- fused preprocessing (coalescing-fixed, R9) ----------------
// lane-contiguous linear mapping: lane l reads float4 at +l*16B (1KB/wave-
// inst), writes bf16 uint2 at +l*8B. hist every 4th block overlaps atomics.
constexpr int NB_CONV4 = (N_NODES_C * 64) / 1024;       // 3125
constexpr int NB_Z = 1;                                 // xb padding zero-fill
constexpr int NB_W1 = (256 * 256) / 256;                // 256
constexpr int NB_W2 = (256 * 128) / 256;                // 128
constexpr int NB_HIST = ((N_EDGES_C / 4) + 255) / 256;  // 782
constexpr int NB_NONH = NB_CONV4 + NB_Z + NB_W1 + NB_W2;  // 3510
constexpr int NB_PRE = NB_NONH + NB_HIST;               // 4292
constexpr int HIST_REGION = NB_HIST * 4;                // 3128

__global__ __launch_bounds__(256) void pre_kernel(
    const float* __restrict__ x, const float* __restrict__ w1,
    const float* __restrict__ w2, const int* __restrict__ dst,
    unsigned short* __restrict__ xb, unsigned short* __restrict__ w1T,
    unsigned short* __restrict__ w2T, int* __restrict__ counts) {
  const int bx = blockIdx.x;
  const int tid = threadIdx.x;
  int l, isHist = 0, h = 0;
  if (bx < HIST_REGION) {
    if ((bx & 3) == 3) { isHist = 1; h = bx >> 2; l = 0; }
    else l = bx - ((bx + 1) >> 2);
  } else {
    l = bx - NB_HIST;
  }

  if (isHist) {
    int e = (h * 256 + tid) * 4;
    if (e < N_EDGES_C) {
      int4 d4 = *(const int4*)(dst + e);
      atomicAdd(&counts[d4.x], 1);
      atomicAdd(&counts[d4.y], 1);
      atomicAdd(&counts[d4.z], 1);
      atomicAdd(&counts[d4.w], 1);
    }
  } else if (l < NB_CONV4) {
    const float4* xv = (const float4*)x;
#pragma unroll
    for (int i = 0; i < 4; ++i) {
      int g = l * 1024 + i * 256 + tid;  // global float4 index, lane-contiguous
      float4 f = xv[g];
      uint2 o;
      o.x = f2bf(f.x) | ((unsigned)f2bf(f.y) << 16);
      o.y = f2bf(f.z) | ((unsigned)f2bf(f.w) << 16);
      *(uint2*)(xb + (size_t)g * 4) = o;
    }
  } else if (l == NB_CONV4) {
    unsigned short* base = xb + (size_t)N_NODES_C * 256;
    uint4 z = make_uint4(0, 0, 0, 0);
#pragma unroll
    for (int i = 0; i < 6; ++i)
      *(uint4*)(base + (size_t)(i * 256 + tid) * 8) = z;
  } else if (l < NB_CONV4 + NB_Z + NB_W1) {
    int idx = (l - NB_CONV4 - NB_Z) * 256 + tid;  // over [N=256][K=256]
    int n = idx >> 8, k = idx & 255;
    w1T[idx] = f2bf(w1[(size_t)k * 256 + n]);
  } else {
    int idx = (l - NB_CONV4 - NB_Z - NB_W1) * 256 + tid;  // over [N=128][K=256]
    int n = idx >> 8, k = idx & 255;
    w2T[idx] = f2bf(w2[(size_t)k * 128 + n]);
  }
}

// ---------------- plain padded CSR (node-id order, deterministic) --------
// R12 lesson: the degree-sort (hist+scatter+perm) was built for the SLICED
// agg; the full-row agg is one-node-per-wave (zero divergence regardless of
// order) and meta is 2% of traffic -- so the sort is dead weight (+20us of
// deterministic-scatter cost in R12). Replace with a plain prefix scan of
// padded lengths (d+3)&~3 in node-id order: bit-deterministic positions,
// two cheap scan kernels (R1-proven structure), no perm indirection.
constexpr int N_SCAN_BLKS = (N_NODES_C + 255) / 256;  // 196

__global__ __launch_bounds__(256) void scan_phase_a(const int* __restrict__ counts,
                                                    int* __restrict__ partial,
                                                    int* __restrict__ blk_sums) {
  __shared__ int s[256];
  const int t = threadIdx.x;
  const int i = blockIdx.x * 256 + t;
  const int d = (i < N_NODES_C) ? counts[i] : 0;
  const int p = (d + 3) & ~3;  // 16B-aligned padded segment length
  s[t] = p;
  __syncthreads();
  for (int off = 1; off < 256; off <<= 1) {
    int u = (t >= off) ? s[t - off] : 0;
    __syncthreads();
    s[t] += u;
    __syncthreads();
  }
  if (i < N_NODES_C) partial[i] = s[t] - p;
  if (t == 255) blk_sums[blockIdx.x] = s[255];
}

// each block redundantly scans the 196 block sums, adds its own offset,
// writes nstart/cursor, and zeroes the pad slots of its nodes' segments.
__global__ __launch_bounds__(256) void scan_phase_bc(const int* __restrict__ counts,
                                                     const int* __restrict__ partial,
                                                     const int* __restrict__ blk_sums,
                                                     int* __restrict__ nstart,
                                                     int* __restrict__ cursor,
                                                     unsigned* __restrict__ s_meta) {
  __shared__ int s[256];
  __shared__ int blk_excl;
  const int t = threadIdx.x;
  const int v = (t < N_SCAN_BLKS) ? blk_sums[t] : 0;
  s[t] = v;
  __syncthreads();
  for (int off = 1; off < 256; off <<= 1) {
    int u = (t >= off) ? s[t - off] : 0;
    __syncthreads();
    s[t] += u;
    __syncthreads();
  }
  if (t == (int)blockIdx.x) blk_excl = s[t] - v;  // this block's exclusive offset
  __syncthreads();
  const int i = blockIdx.x * 256 + t;
  if (i < N_NODES_C) {
    const int d = counts[i];
    const int d4 = (d + 3) & ~3;
    const int start = partial[i] + blk_excl;
    nstart[i] = start;
    cursor[i] = start;
    for (int j = d; j < d4; ++j) s_meta[start + j] = 0;  // zero-weight pads
  }
}

// ---------------- shared GEMM tile (device fn) ----------------
// C natural [M_PAD][ldc] row-major (agg reads full contiguous rows)

#define GLOAD_LDS16(g, l)                                              \
  __builtin_amdgcn_global_load_lds(                                    \
      (__attribute__((address_space(1))) void*)(g),                    \
      (__attribute__((address_space(3))) void*)(l), 16, 0, 0)

__device__ __forceinline__ void gemm_tile(
    const unsigned short* __restrict__ A,   // [M_PAD][256] bf16
    const unsigned short* __restrict__ BT,  // [N][256] bf16
    unsigned short* __restrict__ C,         // [M_PAD][ldc] natural
    int N, int ldc, int row0, int col0, short* Asm, short* Bsm) {
  constexpr int K = 256;
  const int tid = threadIdx.x;
  const int lane = tid & 63, wave = tid >> 6;
  const int wm = wave & 1, wn = wave >> 1;

  const int ch0 = wave * 2, ch1 = wave * 2 + 1;
  const int o0 = ch0 * 512 + lane * 8;
  const int o1 = ch1 * 512 + lane * 8;
  const int r0 = o0 >> 5, c0 = o0 & 31;
  const int r1 = o1 >> 5, c1 = o1 & 31;

  f32x4 acc[4][4] = {};

  for (int k0 = 0; k0 < K; k0 += 32) {
    GLOAD_LDS16(A + (size_t)(row0 + r0) * K + k0 + c0, &Asm[ch0 * 512]);
    GLOAD_LDS16(A + (size_t)(row0 + r1) * K + k0 + c1, &Asm[ch1 * 512]);
    GLOAD_LDS16(BT + (size_t)(col0 + r0) * K + k0 + c0, &Bsm[ch0 * 512]);
    GLOAD_LDS16(BT + (size_t)(col0 + r1) * K + k0 + c1, &Bsm[ch1 * 512]);
    __builtin_amdgcn_s_waitcnt(0);
    __syncthreads();

    bf16x8 af[4], bf[4];
#pragma unroll
    for (int mt = 0; mt < 4; ++mt)
      af[mt] = *(const bf16x8*)&Asm[(wm * 64 + mt * 16 + (lane & 15)) * 32 + (lane >> 4) * 8];
#pragma unroll
    for (int nt = 0; nt < 4; ++nt)
      bf[nt] = *(const bf16x8*)&Bsm[(wn * 64 + nt * 16 + (lane & 15)) * 32 + (lane >> 4) * 8];
#pragma unroll
    for (int mt = 0; mt < 4; ++mt)
#pragma unroll
      for (int nt = 0; nt < 4; ++nt)
        acc[mt][nt] = __builtin_amdgcn_mfma_f32_16x16x32_bf16(af[mt], bf[nt], acc[mt][nt], 0, 0, 0);
    __syncthreads();
  }

  const int cl = lane & 15, rq = (lane >> 4) * 4;
#pragma unroll
  for (int mt = 0; mt < 4; ++mt) {
    const int rbase = row0 + wm * 64 + mt * 16 + rq;
#pragma unroll
    for (int nt = 0; nt < 4; ++nt) {
      const int col = col0 + wn * 64 + nt * 16 + cl;
#pragma unroll
      for (int i = 0; i < 4; ++i)
        C[(size_t)(rbase + i) * ldc + col] = f2bf(acc[mt][nt][i]);
    }
  }
}

// ---------------- fused fill + gemm1 ----------------
// Plain stores for s_meta (positions deterministic from the scan; only
// intra-segment order is racy -> fp-rounding noise only, as in R2-R8).
constexpr int NB_GEMM1 = 2 * (M_PAD / 128);              // 782
constexpr int NB_FILL = ((N_EDGES_C / 4) + 255) / 256;   // 782 (== NB_GEMM1)

__global__ __launch_bounds__(256) void fill_gemm1_kernel(
    const unsigned short* __restrict__ A, const unsigned short* __restrict__ BT,
    unsigned short* __restrict__ C, const int* __restrict__ src,
    const int* __restrict__ dst, const float* __restrict__ ew,
    int* __restrict__ cursor, unsigned* __restrict__ s_meta) {
  __shared__ short Asm[128 * 32];
  __shared__ short Bsm[128 * 32];
  const int b = blockIdx.x;
  if ((b & 1) == 0) {
    const int t = b >> 1;  // [0, NB_GEMM1)
    gemm_tile(A, BT, C, 256, 256, (t >> 1) * 128, (t & 1) * 128, Asm, Bsm);
  } else {
    const int g = (b >> 1) * 256 + threadIdx.x;  // 4-edge group id
    const int e = g * 4;
    if (e < N_EDGES_C) {
      int4 d4 = *(const int4*)(dst + e);
      int4 s4 = *(const int4*)(src + e);
      float4 w4 = *(const float4*)(ew + e);
      unsigned m0 = (unsigned)s4.x | ((unsigned)f2bf(w4.x) << 16);
      unsigned m1 = (unsigned)s4.y | ((unsigned)f2bf(w4.y) << 16);
      unsigned m2 = (unsigned)s4.z | ((unsigned)f2bf(w4.z) << 16);
      unsigned m3 = (unsigned)s4.w | ((unsigned)f2bf(w4.w) << 16);
      int p0 = atomicAdd(&cursor[d4.x], 1);
      int p1 = atomicAdd(&cursor[d4.y], 1);
      int p2 = atomicAdd(&cursor[d4.z], 1);
      int p3 = atomicAdd(&cursor[d4.w], 1);
      s_meta[p0] = m0;
      s_meta[p1] = m1;
      s_meta[p2] = m2;
      s_meta[p3] = m3;
    }
  }
}

__global__ __launch_bounds__(256) void gemm2_kernel(
    const unsigned short* __restrict__ A, const unsigned short* __restrict__ BT,
    unsigned short* __restrict__ C) {
  __shared__ short Asm[128 * 32];
  __shared__ short Bsm[128 * 32];
  gemm_tile(A, BT, C, 128, 128, blockIdx.x * 128, 0, Asm, Bsm);
}

// ---------------- single-pass full-row aggregation (R8 structure) ---------
// one wave = one node (id-order, no perm), lane l owns dims [l*DPL,+DPL);
// each edge = ONE coalesced contiguous row load (512B/256B per wave-inst);
// 2-quad meta software-prefetch pipeline (8 edges ahead) -- measured best
// (R9's no-prefetch split-lane variant regressed 60->72us).

__device__ __forceinline__ void rfma_256(float* acc, unsigned m,
                                         const unsigned short* __restrict__ tp) {
  uint2 v = *(const uint2*)(tp + (size_t)(m & 0xffffu) * 256);
  float wt = bf2f(m >> 16);
  acc[0] += bf2f(v.x & 0xffffu) * wt;
  acc[1] += bf2f(v.x >> 16) * wt;
  acc[2] += bf2f(v.y & 0xffffu) * wt;
  acc[3] += bf2f(v.y >> 16) * wt;
}

__device__ __forceinline__ void rfma_128(float* acc, unsigned m,
                                         const unsigned short* __restrict__ tp) {
  unsigned v = *(const unsigned*)(tp + (size_t)(m & 0xffffu) * 128);
  float wt = bf2f(m >> 16);
  acc[0] += bf2f(v & 0xffffu) * wt;
  acc[1] += bf2f(v >> 16) * wt;
}

template <int OUT_D, bool OUT_BF16>
__global__ __launch_bounds__(256) void agg_row_kernel(
    const unsigned short* __restrict__ sup,   // [M_PAD][OUT_D] natural bf16
    const unsigned* __restrict__ s_meta,      // padded CSR, 4-aligned segs
    const int* __restrict__ nstart, const int* __restrict__ counts,
    const float* __restrict__ bias,
    unsigned short* __restrict__ out_bf, float* __restrict__ out_f, int n_total) {
  constexpr int DPL = OUT_D / 64;  // dims per lane: 4 (layer1) / 2 (layer2)
  const int tid = threadIdx.x;
  const int wv = tid >> 6;   // wave in block (0..3) = node
  const int lane = tid & 63;
  const int n = blockIdx.x * 4 + wv;
  if (n >= n_total) return;
  const bool valid = n < N_NODES_C;
  const unsigned short* tp = sup + lane * DPL;

  float acc[DPL] = {};
  int s = 0, dg = 0;
  if (valid) {
    s = nstart[n];
    dg = counts[n];
  }
  const int nq = (dg + 3) >> 2;  // 4-edge quads (pads are zero-weight)
  const uint4* mp = (const uint4*)(s_meta + s);

#define RFMA(mm)                              \
  do {                                        \
    if (OUT_D == 256) rfma_256(acc, mm, tp);  \
    else rfma_128(acc, mm, tp);               \
  } while (0)

  if (nq > 0) {
    uint4 m0 = mp[0];
    uint4 m1 = (nq > 1) ? mp[1] : make_uint4(0, 0, 0, 0);
    int q = 0;
    for (; q + 2 < nq; q += 2) {
      uint4 p0 = mp[q + 2];
      uint4 p1 = mp[q + 3];  // may read 16B past segment end (buffer slack)
      RFMA(m0.x); RFMA(m0.y); RFMA(m0.z); RFMA(m0.w);
      RFMA(m1.x); RFMA(m1.y); RFMA(m1.z); RFMA(m1.w);
      m0 = p0;
      m1 = p1;
    }
    RFMA(m0.x); RFMA(m0.y); RFMA(m0.z); RFMA(m0.w);
    if (q + 1 < nq) { RFMA(m1.x); RFMA(m1.y); RFMA(m1.z); RFMA(m1.w); }
  }
#undef RFMA

  const int dbase = lane * DPL;
  if (OUT_BF16) {
    unsigned short o[DPL];
#pragma unroll
    for (int j = 0; j < DPL; ++j) {
      if (valid) {
        float v = acc[j] + bias[dbase + j];
        v = v >= 0.f ? v : NEG_SLOPE * v;
        o[j] = f2bf(v);
      } else {
        o[j] = 0;
      }
    }
    uint2 pk;
    pk.x = o[0] | ((unsigned)o[1] << 16);
    pk.y = o[2] | ((unsigned)o[3] << 16);
    *(uint2*)(out_bf + (size_t)n * OUT_D + dbase) = pk;  // 8B/lane coalesced
  } else if (valid) {
    float r[DPL];
#pragma unroll
    for (int j = 0; j < DPL; ++j) {
      float v = acc[j] + bias[dbase + j];
      r[j] = v >= 0.f ? v : NEG_SLOPE * v;
    }
    *(float2*)(out_f + (size_t)n * OUT_D + dbase) = make_float2(r[0], r[1]);
  }
}

// ---------------- launch ----------------

extern "C" void kernel_launch(void* const* d_in, const int* in_sizes, int n_in,
                              void* d_out, int out_size, void* d_ws, size_t ws_size,
                              hipStream_t stream) {
  const float* x  = (const float*)d_in[0];   // [50000,256]
  const float* w1 = (const float*)d_in[1];   // [256,256]
  const float* b1 = (const float*)d_in[2];   // [256]
  const float* w2 = (const float*)d_in[3];   // [256,128]
  const float* b2 = (const float*)d_in[4];   // [128]
  const int*   src = (const int*)d_in[5];    // [800000]
  const int*   dst = (const int*)d_in[6];    // [800000]
  const float* ew  = (const float*)d_in[7];  // [800000]
  float* out = (float*)d_out;                // [50000,128]

  unsigned short* xb   = (unsigned short*)d_ws;              // M_PAD*256
  unsigned short* a2b  = xb + (size_t)M_PAD * 256;           // M_PAD*256
  unsigned short* sup1 = a2b + (size_t)M_PAD * 256;          // [M_PAD][256]
  unsigned short* sup2 = sup1 + (size_t)M_PAD * 256;         // [M_PAD][128]
  unsigned short* w1T  = sup2 + (size_t)M_PAD * 128;         // 256*256
  unsigned short* w2T  = w1T + 256 * 256;                    // 128*256
  int* counts  = (int*)(w2T + 128 * 256);                    // 50000
  int* cursor  = counts + N_NODES_C;                         // 50000
  int* nstart  = cursor + N_NODES_C;                         // 50000
  int* partial = nstart + N_NODES_C;                         // 50000
  int* blk_sums= partial + N_NODES_C;                        // 256
  unsigned* s_meta = (unsigned*)(blk_sums + 256);            // META_CAP * 4B

  // zero counts, then fused {conv_x, w1T, w2T, degree histogram}
  hipMemsetAsync(counts, 0, N_NODES_C * sizeof(int), stream);
  pre_kernel<<<NB_PRE, 256, 0, stream>>>(x, w1, w2, dst, xb, w1T, w2T, counts);

  // padded CSR scan (node-id order, deterministic) + pad zeroing
  scan_phase_a<<<N_SCAN_BLKS, 256, 0, stream>>>(counts, partial, blk_sums);
  scan_phase_bc<<<N_SCAN_BLKS, 256, 0, stream>>>(counts, partial, blk_sums,
                                                 nstart, cursor, s_meta);

  // fused: CSR bucket fill + gemm1 (one dispatch)
  fill_gemm1_kernel<<<NB_GEMM1 + NB_FILL, 256, 0, stream>>>(
      xb, w1T, sup1, src, dst, ew, cursor, s_meta);

  // layer-1 aggregation -> a2b (bf16, lrelu+bias fused); 4 nodes/block
  agg_row_kernel<256, true><<<M_PAD / 4, 256, 0, stream>>>(
      sup1, s_meta, nstart, counts, b1, a2b, nullptr, M_PAD);

  // layer 2
  gemm2_kernel<<<M_PAD / 128, 256, 0, stream>>>(a2b, w2T, sup2);
  agg_row_kernel<128, false><<<N_NODES_C / 4, 256, 0, stream>>>(
      sup2, s_meta, nstart, counts, b2, nullptr, out, N_NODES_C);
}